// Round 5
// baseline (216.741 us; speedup 1.0000x reference)
//
#include <hip/hip_runtime.h>

typedef __attribute__((ext_vector_type(8))) short short8;
typedef __attribute__((ext_vector_type(4))) float f32x4;
typedef __attribute__((ext_vector_type(4))) float f4;
typedef __attribute__((ext_vector_type(4))) unsigned short u16x4;

__device__ __forceinline__ unsigned short f2bf(float f) {
    union { float f; unsigned int u; } v; v.f = f;
    unsigned int r = v.u + 0x7fffu + ((v.u >> 16) & 1u);
    return (unsigned short)(r >> 16);
}
__device__ __forceinline__ float bf2f(unsigned short h) {
    union { unsigned int u; float f; } v; v.u = ((unsigned int)h) << 16;
    return v.f;
}
__device__ __forceinline__ void gload_lds16(const void* g, void* l) {
    __builtin_amdgcn_global_load_lds(
        (const __attribute__((address_space(1))) unsigned int*)g,
        (__attribute__((address_space(3))) unsigned int*)l, 16, 0, 0);
}

// ---------------- conversions ----------------

__global__ void conv_x(const float* __restrict__ x, unsigned short* __restrict__ xb) {
    int i = blockIdx.x * 256 + threadIdx.x;
    f4 v = ((const f4*)x)[i];
    u16x4 o;
    o[0] = f2bf(v[0]); o[1] = f2bf(v[1]); o[2] = f2bf(v[2]); o[3] = f2bf(v[3]);
    ((u16x4*)xb)[i] = o;
}

__global__ void conv_wqkvt(const float* __restrict__ wq, const float* __restrict__ wkv,
                           unsigned short* __restrict__ wt) {
    __shared__ float tile[64 * 65];
    const int d0 = blockIdx.x * 64, f0 = blockIdx.y * 64;
    const int head = f0 >> 7;
    const int h0 = f0 & 127;
    const float* src;
    if (head < 16) src = wq + (size_t)head * 2048 * 128;
    else           src = wkv + (size_t)(head - 16) * 2048 * 128;
    {
        int hh = threadIdx.x & 63, dq = threadIdx.x >> 6;
        #pragma unroll
        for (int r = 0; r < 16; ++r) {
            int dd = r * 4 + dq;
            tile[dd * 65 + hh] = src[(size_t)(d0 + dd) * 128 + h0 + hh];
        }
    }
    __syncthreads();
    {
        int dd = threadIdx.x & 63, fq = threadIdx.x >> 6;
        #pragma unroll
        for (int r = 0; r < 16; ++r) {
            int fl = r * 4 + fq;
            wt[(size_t)(f0 + fl) * 2048 + d0 + dd] = f2bf(tile[dd * 65 + fl]);
        }
    }
}

__global__ void conv_wot(const float* __restrict__ wo, unsigned short* __restrict__ wt) {
    __shared__ float tile[64 * 65];
    const int d0 = blockIdx.x * 64, r0 = blockIdx.y * 64;
    int cc = threadIdx.x & 63, rq = threadIdx.x >> 6;
    #pragma unroll
    for (int r = 0; r < 16; ++r) {
        int rr = r * 4 + rq;
        tile[rr * 65 + cc] = wo[(size_t)(r0 + rr) * 2048 + d0 + cc];
    }
    __syncthreads();
    #pragma unroll
    for (int r = 0; r < 16; ++r) {
        int rr = r * 4 + rq;
        wt[(size_t)(d0 + rr) * 2048 + r0 + cc] = f2bf(tile[cc * 65 + rr]);
    }
}

// ---------------- 8-phase 256x256 GEMM, generalized (QKV + split-K out-proj) ----------------
// C[.][.] = A[. x K] * Bt[. x K]^T (bf16 in/out). ldk = row stride of A,Bt.
// nt = K-tiles (of 64) this block processes. ksplit: by = (mblock<<1)|slice; each
// slice covers K-range [slice*nt*64, ...) and writes C + slice*cstride.
// MFMA ordering is kk-major: dependent-accumulator reuse distance = 8 MFMAs.

__global__ __launch_bounds__(512, 2)
void gemm8p(const unsigned short* __restrict__ A,
            const unsigned short* __restrict__ Bt,
            unsigned short* __restrict__ C,
            int ldk, int ldc, int nt, int ksplit, size_t cstride) {
    __shared__ __align__(16) unsigned short LDS[65536];
    const int tid = threadIdx.x, lane = tid & 63, w = tid >> 6;
    const int wr = w >> 2, wc = w & 3;
    const int l15 = lane & 15, l4 = lane >> 4;
    int nwg = gridDim.x * gridDim.y;
    int wg = blockIdx.y * gridDim.x + blockIdx.x;
    int swz = (wg & 7) * (nwg >> 3) + (wg >> 3);
    int bx = swz % gridDim.x, by = swz / gridDim.x;
    int slice = 0;
    if (ksplit) { slice = by & 1; by >>= 1; }
    unsigned short* Cs = C + (size_t)slice * cstride;
    const int brow = by * 256, bcol = bx * 256;
    const size_t koff = (size_t)slice * nt * 64;
    const int wg_a = w & 3;
    const int wg_b = wr;
    const int rA = wg_a * 8 + (lane >> 3);
    const int rB = wg_b * 8 + (lane >> 3);
    const int cgS = ((lane & 7) ^ (lane >> 3)) * 8;
    const unsigned short* aP = A + (size_t)(brow + wr * 128 + rA) * ldk + koff + cgS;
    const unsigned short* bP = Bt + (size_t)(bcol + wc * 64 + rB) * ldk + koff + cgS;
    const int ldsA0 = wr * 8192 + (wg_a * 64 + lane) * 8;
    const int ldsB0 = wc * 4096 + (wg_b * 64 + lane) * 8;
    const int aRd = (wr * 128 + l15) * 64;
    const int bRd = (wc * 64 + l15) * 64;
    const int c0 = ((0 + l4) ^ (l15 & 7)) * 8;
    const int c1 = ((4 + l4) ^ (l15 & 7)) * 8;
    f32x4 acc[8][4] = {};
    gload_lds16(aP,                    &LDS[ldsA0]);
    gload_lds16(bP,                    &LDS[16384 + ldsB0]);
    gload_lds16(aP + (size_t)32 * ldk, &LDS[ldsA0 + 2048]);
    gload_lds16(bP + (size_t)16 * ldk, &LDS[16384 + ldsB0 + 1024]);
    gload_lds16(bP + (size_t)32 * ldk, &LDS[16384 + ldsB0 + 2048]);
    gload_lds16(bP + (size_t)48 * ldk, &LDS[16384 + ldsB0 + 3072]);
    gload_lds16(aP + (size_t)64 * ldk, &LDS[ldsA0 + 4096]);
    gload_lds16(aP + (size_t)96 * ldk, &LDS[ldsA0 + 6144]);
    asm volatile("s_waitcnt vmcnt(4)" ::: "memory");
    __builtin_amdgcn_s_barrier();
    __builtin_amdgcn_sched_barrier(0);

    short8 af[4][2], bl[2][2], bh[2][2];
    for (int t = 0; t < nt; ++t) {
        const int bufA = (t & 1) << 15, bufB = bufA + 16384;
        const bool pf = (t + 1) < nt;
        const int sA = ((t + 1) & 1) << 15, sB = sA + 16384;
        const unsigned short* ap = aP + (t + 1) * 64;
        const unsigned short* bp = bP + (t + 1) * 64;
        // ===== P1 : m0-3 x n0-1 =====
        #pragma unroll
        for (int m = 0; m < 4; ++m) {
            af[m][0] = *(const short8*)&LDS[bufA + aRd + m * 1024 + c0];
            af[m][1] = *(const short8*)&LDS[bufA + aRd + m * 1024 + c1];
        }
        #pragma unroll
        for (int n = 0; n < 2; ++n) {
            bl[n][0] = *(const short8*)&LDS[bufB + bRd + n * 1024 + c0];
            bl[n][1] = *(const short8*)&LDS[bufB + bRd + n * 1024 + c1];
        }
        if (pf) { gload_lds16(ap, &LDS[sA + ldsA0]);
                  gload_lds16(bp, &LDS[sB + ldsB0]); }
        __builtin_amdgcn_s_barrier();
        __builtin_amdgcn_sched_barrier(0);
        __builtin_amdgcn_s_setprio(1);
        #pragma unroll
        for (int kk = 0; kk < 2; ++kk)
            #pragma unroll
            for (int m = 0; m < 4; ++m)
                #pragma unroll
                for (int n = 0; n < 2; ++n)
                    acc[m][n] = __builtin_amdgcn_mfma_f32_16x16x32_bf16(af[m][kk], bl[n][kk], acc[m][n], 0, 0, 0);
        __builtin_amdgcn_s_setprio(0);
        asm volatile("s_waitcnt vmcnt(4)" ::: "memory");
        __builtin_amdgcn_s_barrier();
        __builtin_amdgcn_sched_barrier(0);
        // ===== P2 : m0-3 x n2-3 =====
        #pragma unroll
        for (int n = 0; n < 2; ++n) {
            bh[n][0] = *(const short8*)&LDS[bufB + bRd + (n + 2) * 1024 + c0];
            bh[n][1] = *(const short8*)&LDS[bufB + bRd + (n + 2) * 1024 + c1];
        }
        if (pf) { gload_lds16(ap + (size_t)32 * ldk, &LDS[sA + ldsA0 + 2048]);
                  gload_lds16(bp + (size_t)16 * ldk, &LDS[sB + ldsB0 + 1024]); }
        __builtin_amdgcn_s_barrier();
        __builtin_amdgcn_sched_barrier(0);
        __builtin_amdgcn_s_setprio(1);
        #pragma unroll
        for (int kk = 0; kk < 2; ++kk)
            #pragma unroll
            for (int m = 0; m < 4; ++m)
                #pragma unroll
                for (int n = 0; n < 2; ++n)
                    acc[m][n + 2] = __builtin_amdgcn_mfma_f32_16x16x32_bf16(af[m][kk], bh[n][kk], acc[m][n + 2], 0, 0, 0);
        __builtin_amdgcn_s_setprio(0);
        asm volatile("s_waitcnt vmcnt(4)" ::: "memory");
        __builtin_amdgcn_s_barrier();
        __builtin_amdgcn_sched_barrier(0);
        // ===== P3 : m4-7 x n0-1 =====
        #pragma unroll
        for (int m = 0; m < 4; ++m) {
            af[m][0] = *(const short8*)&LDS[bufA + aRd + (m + 4) * 1024 + c0];
            af[m][1] = *(const short8*)&LDS[bufA + aRd + (m + 4) * 1024 + c1];
        }
        if (pf) { gload_lds16(bp + (size_t)32 * ldk, &LDS[sB + ldsB0 + 2048]);
                  gload_lds16(bp + (size_t)48 * ldk, &LDS[sB + ldsB0 + 3072]); }
        __builtin_amdgcn_s_barrier();
        __builtin_amdgcn_sched_barrier(0);
        __builtin_amdgcn_s_setprio(1);
        #pragma unroll
        for (int kk = 0; kk < 2; ++kk)
            #pragma unroll
            for (int m = 0; m < 4; ++m)
                #pragma unroll
                for (int n = 0; n < 2; ++n)
                    acc[m + 4][n] = __builtin_amdgcn_mfma_f32_16x16x32_bf16(af[m][kk], bl[n][kk], acc[m + 4][n], 0, 0, 0);
        __builtin_amdgcn_s_setprio(0);
        __builtin_amdgcn_s_barrier();
        __builtin_amdgcn_sched_barrier(0);
        // ===== P4 : m4-7 x n2-3 =====
        if (pf) { gload_lds16(ap + (size_t)64 * ldk, &LDS[sA + ldsA0 + 4096]);
                  gload_lds16(ap + (size_t)96 * ldk, &LDS[sA + ldsA0 + 6144]); }
        __builtin_amdgcn_s_barrier();
        __builtin_amdgcn_sched_barrier(0);
        __builtin_amdgcn_s_setprio(1);
        #pragma unroll
        for (int kk = 0; kk < 2; ++kk)
            #pragma unroll
            for (int m = 0; m < 4; ++m)
                #pragma unroll
                for (int n = 0; n < 2; ++n)
                    acc[m + 4][n + 2] = __builtin_amdgcn_mfma_f32_16x16x32_bf16(af[m][kk], bh[n][kk], acc[m + 4][n + 2], 0, 0, 0);
        __builtin_amdgcn_s_setprio(0);
        asm volatile("s_waitcnt vmcnt(4)" ::: "memory");
        __builtin_amdgcn_s_barrier();
        __builtin_amdgcn_sched_barrier(0);
    }
    #pragma unroll
    for (int m = 0; m < 8; ++m)
        #pragma unroll
        for (int n = 0; n < 4; ++n)
            #pragma unroll
            for (int j = 0; j < 4; ++j) {
                int row = brow + wr * 128 + m * 16 + l4 * 4 + j;
                int col = bcol + wc * 64 + n * 16 + l15;
                Cs[(size_t)row * ldc + col] = f2bf(acc[m][n][j]);
            }
}

// ---------------- split-K reduce: out = bf2f(p0) + bf2f(p1) ----------------
__global__ void addparts(const unsigned short* __restrict__ p0,
                         const unsigned short* __restrict__ p1,
                         float* __restrict__ out) {
    int i = blockIdx.x * 256 + threadIdx.x;
    short8 a = ((const short8*)p0)[i];
    short8 b = ((const short8*)p1)[i];
    f4 lo, hi;
    #pragma unroll
    for (int j = 0; j < 4; ++j)
        lo[j] = bf2f((unsigned short)a[j]) + bf2f((unsigned short)b[j]);
    #pragma unroll
    for (int j = 0; j < 4; ++j)
        hi[j] = bf2f((unsigned short)a[j + 4]) + bf2f((unsigned short)b[j + 4]);
    ((f4*)out)[2 * i] = lo;
    ((f4*)out)[2 * i + 1] = hi;
}

// ---------------- RoPE (Q/K only) ----------------
__global__ void rope_reshape(const unsigned short* __restrict__ qkv,
                             const int* __restrict__ segpos,
                             unsigned short* __restrict__ q_r,
                             unsigned short* __restrict__ k_r) {
    const int bt = blockIdx.x;
    const int hd = blockIdx.y * 2 + (threadIdx.x >> 7);  // 0..23
    const int b = bt >> 11, t = bt & 2047;
    const int h = threadIdx.x & 127;
    const unsigned short* in = (hd < 16)
        ? qkv + (size_t)bt * 4096 + hd * 128
        : qkv + (size_t)bt * 4096 + 2048 + (hd - 16) * 128;
    int pos = segpos[bt];
    int i = h & 63;
    float inv_ts = __expf((float)i * (-9.210340371976184f / 64.f));
    float ang = (float)pos * inv_ts;
    float s = __sinf(ang), c = __cosf(ang);
    float x1 = bf2f(in[i]);
    float x2 = bf2f(in[i + 64]);
    float o = (h < 64) ? (x1 * c - x2 * s) : (x2 * c + x1 * s);
    if (hd < 16) {
        o *= 0.08838834764831845f;
        q_r[((size_t)((b * 16 + hd) * 2048 + t)) * 128 + h] = f2bf(o);
    } else {
        int kh = hd - 16;
        k_r[((size_t)((b * 8 + kh) * 2048 + t)) * 128 + h] = f2bf(o);
    }
}

// ---------------- V transpose (LDS-tiled) ----------------
__global__ void v_transpose(const unsigned short* __restrict__ qkv,
                            unsigned short* __restrict__ v_t) {
    __shared__ unsigned short tile[64][72];
    const int tt0 = blockIdx.x * 64;
    const int kh = blockIdx.y >> 1, hb = (blockIdx.y & 1) * 64;
    const int b = blockIdx.z;
    int c = threadIdx.x & 63, rq = threadIdx.x >> 6;
    #pragma unroll
    for (int r = 0; r < 16; ++r) {
        int tt = r * 4 + rq;
        tile[tt][c] = qkv[(size_t)(b * 2048 + tt0 + tt) * 4096 + 3072 + kh * 128 + hb + c];
    }
    __syncthreads();
    #pragma unroll
    for (int r = 0; r < 16; ++r) {
        int hr = r * 4 + rq;
        v_t[((size_t)(b * 8 + kh) * 128 + hb + hr) * 2048 + tt0 + c] = tile[c][hr];
    }
}

// ---------------- flash attention (fixed-max softmax via soft-cap bound) ----------------

__device__ __forceinline__ void stage_kv(const unsigned short* kbase, const unsigned short* vbase,
                                         unsigned short* Ksb, unsigned short* Vtb,
                                         int st, int tid) {
    #pragma unroll
    for (int r = 0; r < 2; ++r) {
        int e = (r * 512 + tid) * 8;
        int krow = e >> 7, kcol = e & 127;
        gload_lds16(kbase + (size_t)(st * 64 + krow) * 128 + (kcol ^ ((krow & 7) << 3)), Ksb + e);
        int vrow = e >> 6, vcol = e & 63;
        gload_lds16(vbase + (size_t)vrow * 2048 + st * 64 + (vcol ^ ((vrow & 7) << 3)), Vtb + e);
    }
}

__global__ __launch_bounds__(512, 4)
void attn_kernel(const unsigned short* __restrict__ q_r,
                 const unsigned short* __restrict__ k_r,
                 const unsigned short* __restrict__ v_t,
                 unsigned short* __restrict__ enc) {
    __shared__ __align__(16) unsigned short Ks[2][64 * 128];
    __shared__ __align__(16) unsigned short Vt[2][128 * 64];
    __shared__ __align__(16) unsigned short Pl[8][16 * 64];
    const int tid = threadIdx.x, lane = tid & 63, wave = tid >> 6;
    const int l15 = lane & 15, l4 = lane >> 4;
    const int flat = blockIdx.x;
    const int xcd = flat & 7, g = flat >> 3;
    const int pair = xcd * 2 + (g >> 5);
    const int qb = 31 - (g & 31);
    const int kh = pair >> 1, b = pair & 1;
    const int n = kh * 2 + (wave >> 2);
    const int wq = wave & 3;
    short8 qf[4];
    {
        const unsigned short* qp =
            q_r + ((size_t)((b * 16 + n) * 2048 + qb * 64 + wq * 16 + l15)) * 128 + l4 * 8;
        #pragma unroll
        for (int kk = 0; kk < 4; ++kk) qf[kk] = *(const short8*)(qp + kk * 32);
    }
    f32x4 Of[8] = {};
    float lrow[4] = {};
    int t_lo = qb * 64 - 1023; if (t_lo < 0) t_lo = 0;
    const int st0 = t_lo >> 6;
    const unsigned short* kbase = k_r + (size_t)(b * 8 + kh) * 2048 * 128;
    const unsigned short* vbase = v_t + (size_t)(b * 8 + kh) * 128 * 2048;

    stage_kv(kbase, vbase, Ks[0], Vt[0], st0, tid);
    __syncthreads();
    int cur = 0;
    for (int st = st0; st <= qb; ++st) {
        if (st < qb)
            stage_kv(kbase, vbase, Ks[cur ^ 1], Vt[cur ^ 1], st + 1, tid);
        // ---- QK^T (kk-major: sf[nc] reuse distance = 4) ----
        f32x4 sf[4] = {};
        {
            int sw = (l15 & 7) << 3;
            #pragma unroll
            for (int kk = 0; kk < 4; ++kk)
                #pragma unroll
                for (int nc = 0; nc < 4; ++nc) {
                    short8 bfr = *(const short8*)&Ks[cur][(nc * 16 + l15) * 128 + ((kk * 32 + l4 * 8) ^ sw)];
                    sf[nc] = __builtin_amdgcn_mfma_f32_16x16x32_bf16(qf[kk], bfr, sf[nc], 0, 0, 0);
                }
        }
        // ---- softcap + fixed-max softmax: p = exp(50*tanh(x/50) - 50) ----
        const int mode = (st == qb) ? 1 : ((qb >= 16 && st == st0) ? 2 : 0);
        #pragma unroll
        for (int j = 0; j < 4; ++j) {
            int trow = qb * 64 + wq * 16 + l4 * 4 + j;
            int prow = l4 * 4 + j;
            int psw = (prow & 7) << 3;
            #pragma unroll
            for (int nc = 0; nc < 4; ++nc) {
                float ex = __expf(sf[nc][j] * 0.04f);
                float p = __expf(-100.f * __builtin_amdgcn_rcpf(ex + 1.f));
                if (mode) {
                    int s = st * 64 + nc * 16 + l15;
                    bool ok = (mode == 1) ? (s <= trow) : (s >= trow - 1023);
                    p = ok ? p : 0.f;
                }
                lrow[j] += p;
                Pl[wave][prow * 64 + ((nc * 16 + l15) ^ psw)] = f2bf(p);
            }
        }
        // ---- PV ----
        {
            int asw = (l15 & 7) << 3;
            #pragma unroll
            for (int ks = 0; ks < 2; ++ks) {
                short8 af = *(const short8*)&Pl[wave][l15 * 64 + ((ks * 32 + l4 * 8) ^ asw)];
                #pragma unroll
                for (int hc = 0; hc < 8; ++hc) {
                    int vrow = hc * 16 + l15;
                    short8 bfr = *(const short8*)&Vt[cur][vrow * 64 + ((ks * 32 + l4 * 8) ^ asw)];
                    Of[hc] = __builtin_amdgcn_mfma_f32_16x16x32_bf16(af, bfr, Of[hc], 0, 0, 0);
                }
            }
        }
        __syncthreads();
        cur ^= 1;
    }
    float inv[4];
    #pragma unroll
    for (int j = 0; j < 4; ++j) {
        float l = lrow[j];
        l += __shfl_xor(l, 1); l += __shfl_xor(l, 2);
        l += __shfl_xor(l, 4); l += __shfl_xor(l, 8);
        inv[j] = 1.f / l;
    }
    #pragma unroll
    for (int hc = 0; hc < 8; ++hc)
        #pragma unroll
        for (int j = 0; j < 4; ++j) {
            size_t row = (size_t)(b * 2048 + qb * 64 + wq * 16 + l4 * 4 + j);
            enc[row * 2048 + n * 128 + hc * 16 + l15] = f2bf(Of[hc][j] * inv[j]);
        }
}

// ---------------- launch ----------------

extern "C" void kernel_launch(void* const* d_in, const int* in_sizes, int n_in,
                              void* d_out, int out_size, void* d_ws, size_t ws_size,
                              hipStream_t stream) {
    const float* x   = (const float*)d_in[0];
    const int* segp  = (const int*)d_in[1];
    const float* wq  = (const float*)d_in[3];
    const float* wkv = (const float*)d_in[4];
    const float* wo  = (const float*)d_in[5];
    float* out = (float*)d_out;
    char* ws = (char*)d_ws;
    if (ws_size < ((size_t)96 << 20)) return;

    unsigned short* xb    = (unsigned short*)(ws);                       // 16 MiB
    unsigned short* wqkvt = (unsigned short*)(ws + ((size_t)16 << 20));  // 16 MiB
    unsigned short* qkv   = (unsigned short*)(ws + ((size_t)32 << 20));  // 32 MiB
    unsigned short* q_r   = (unsigned short*)(ws + ((size_t)64 << 20));  // 16 MiB
    unsigned short* k_r   = (unsigned short*)(ws + ((size_t)80 << 20));  // 8 MiB
    unsigned short* v_t   = (unsigned short*)(ws + ((size_t)88 << 20));  // 8 MiB
    unsigned short* wo_t  = (unsigned short*)(ws + ((size_t)16 << 20));  // reuse wqkvt (after QKV gemm)
    unsigned short* enc   = (unsigned short*)(ws + ((size_t)32 << 20));  // reuse qkv
    unsigned short* part  = (unsigned short*)(ws + ((size_t)64 << 20));  // 32 MiB, reuse q_r/k_r/v_t

    conv_x<<<8192, 256, 0, stream>>>(x, xb);
    conv_wqkvt<<<dim3(32, 64), 256, 0, stream>>>(wq, wkv, wqkvt);
    // QKV: M=4096, N=4096, K=2048
    gemm8p<<<dim3(16, 16), 512, 0, stream>>>(xb, wqkvt, qkv, 2048, 4096, 32, 0, 0);
    rope_reshape<<<dim3(4096, 12), 256, 0, stream>>>(qkv, segp, q_r, k_r);
    v_transpose<<<dim3(32, 16, 2), 256, 0, stream>>>(qkv, v_t);
    conv_wot<<<dim3(32, 32), 256, 0, stream>>>(wo, wo_t);
    attn_kernel<<<512, 512, 0, stream>>>(q_r, k_r, v_t, enc);
    // out-proj: M=4096, N=2048, K=2048, split-K x2 -> bf16 partials
    gemm8p<<<dim3(8, 32), 512, 0, stream>>>(enc, wo_t, part, 2048, 2048, 16, 1, (size_t)4096 * 2048);
    addparts<<<4096, 256, 0, stream>>>(part, part + (size_t)4096 * 2048, out);
}

// Round 6
// 216.154 us; speedup vs baseline: 1.0027x; 1.0027x over previous
//
#include <hip/hip_runtime.h>

typedef __attribute__((ext_vector_type(8))) short short8;
typedef __attribute__((ext_vector_type(4))) float f32x4;
typedef __attribute__((ext_vector_type(4))) float f4;
typedef __attribute__((ext_vector_type(4))) unsigned short u16x4;

__device__ __forceinline__ unsigned short f2bf(float f) {
    union { float f; unsigned int u; } v; v.f = f;
    unsigned int r = v.u + 0x7fffu + ((v.u >> 16) & 1u);
    return (unsigned short)(r >> 16);
}
__device__ __forceinline__ float bf2f(unsigned short h) {
    union { unsigned int u; float f; } v; v.u = ((unsigned int)h) << 16;
    return v.f;
}
__device__ __forceinline__ void gload_lds16(const void* g, void* l) {
    __builtin_amdgcn_global_load_lds(
        (const __attribute__((address_space(1))) unsigned int*)g,
        (__attribute__((address_space(3))) unsigned int*)l, 16, 0, 0);
}

// ---------------- conversions ----------------

__global__ void conv_x(const float* __restrict__ x, unsigned short* __restrict__ xb) {
    int i = blockIdx.x * 256 + threadIdx.x;
    f4 v = ((const f4*)x)[i];
    u16x4 o;
    o[0] = f2bf(v[0]); o[1] = f2bf(v[1]); o[2] = f2bf(v[2]); o[3] = f2bf(v[3]);
    ((u16x4*)xb)[i] = o;
}

// QUERY_SCALE folded into q-head weights (rope is linear; scale commutes)
__global__ void conv_wqkvt(const float* __restrict__ wq, const float* __restrict__ wkv,
                           unsigned short* __restrict__ wt) {
    __shared__ float tile[64 * 65];
    const int d0 = blockIdx.x * 64, f0 = blockIdx.y * 64;
    const int head = f0 >> 7;
    const int h0 = f0 & 127;
    const float* src;
    float scl;
    if (head < 16) { src = wq + (size_t)head * 2048 * 128; scl = 0.08838834764831845f; }
    else           { src = wkv + (size_t)(head - 16) * 2048 * 128; scl = 1.f; }
    {
        int hh = threadIdx.x & 63, dq = threadIdx.x >> 6;
        #pragma unroll
        for (int r = 0; r < 16; ++r) {
            int dd = r * 4 + dq;
            tile[dd * 65 + hh] = src[(size_t)(d0 + dd) * 128 + h0 + hh] * scl;
        }
    }
    __syncthreads();
    {
        int dd = threadIdx.x & 63, fq = threadIdx.x >> 6;
        #pragma unroll
        for (int r = 0; r < 16; ++r) {
            int fl = r * 4 + fq;
            wt[(size_t)(f0 + fl) * 2048 + d0 + dd] = f2bf(tile[dd * 65 + fl]);
        }
    }
}

__global__ void conv_wot(const float* __restrict__ wo, unsigned short* __restrict__ wt) {
    __shared__ float tile[64 * 65];
    const int d0 = blockIdx.x * 64, r0 = blockIdx.y * 64;
    int cc = threadIdx.x & 63, rq = threadIdx.x >> 6;
    #pragma unroll
    for (int r = 0; r < 16; ++r) {
        int rr = r * 4 + rq;
        tile[rr * 65 + cc] = wo[(size_t)(r0 + rr) * 2048 + d0 + cc];
    }
    __syncthreads();
    #pragma unroll
    for (int r = 0; r < 16; ++r) {
        int rr = r * 4 + rq;
        wt[(size_t)(d0 + rr) * 2048 + r0 + cc] = f2bf(tile[cc * 65 + rr]);
    }
}

// ---------------- 8-phase 256x256 GEMM, generalized (QKV + split-K out-proj) ----------------

__global__ __launch_bounds__(512, 2)
void gemm8p(const unsigned short* __restrict__ A,
            const unsigned short* __restrict__ Bt,
            unsigned short* __restrict__ C,
            int ldk, int ldc, int nt, int ksplit, size_t cstride) {
    __shared__ __align__(16) unsigned short LDS[65536];
    const int tid = threadIdx.x, lane = tid & 63, w = tid >> 6;
    const int wr = w >> 2, wc = w & 3;
    const int l15 = lane & 15, l4 = lane >> 4;
    int nwg = gridDim.x * gridDim.y;
    int wg = blockIdx.y * gridDim.x + blockIdx.x;
    int swz = (wg & 7) * (nwg >> 3) + (wg >> 3);
    int bx = swz % gridDim.x, by = swz / gridDim.x;
    int slice = 0;
    if (ksplit) { slice = by & 1; by >>= 1; }
    unsigned short* Cs = C + (size_t)slice * cstride;
    const int brow = by * 256, bcol = bx * 256;
    const size_t koff = (size_t)slice * nt * 64;
    const int wg_a = w & 3;
    const int wg_b = wr;
    const int rA = wg_a * 8 + (lane >> 3);
    const int rB = wg_b * 8 + (lane >> 3);
    const int cgS = ((lane & 7) ^ (lane >> 3)) * 8;
    const unsigned short* aP = A + (size_t)(brow + wr * 128 + rA) * ldk + koff + cgS;
    const unsigned short* bP = Bt + (size_t)(bcol + wc * 64 + rB) * ldk + koff + cgS;
    const int ldsA0 = wr * 8192 + (wg_a * 64 + lane) * 8;
    const int ldsB0 = wc * 4096 + (wg_b * 64 + lane) * 8;
    const int aRd = (wr * 128 + l15) * 64;
    const int bRd = (wc * 64 + l15) * 64;
    const int c0 = ((0 + l4) ^ (l15 & 7)) * 8;
    const int c1 = ((4 + l4) ^ (l15 & 7)) * 8;
    f32x4 acc[8][4] = {};
    gload_lds16(aP,                    &LDS[ldsA0]);
    gload_lds16(bP,                    &LDS[16384 + ldsB0]);
    gload_lds16(aP + (size_t)32 * ldk, &LDS[ldsA0 + 2048]);
    gload_lds16(bP + (size_t)16 * ldk, &LDS[16384 + ldsB0 + 1024]);
    gload_lds16(bP + (size_t)32 * ldk, &LDS[16384 + ldsB0 + 2048]);
    gload_lds16(bP + (size_t)48 * ldk, &LDS[16384 + ldsB0 + 3072]);
    gload_lds16(aP + (size_t)64 * ldk, &LDS[ldsA0 + 4096]);
    gload_lds16(aP + (size_t)96 * ldk, &LDS[ldsA0 + 6144]);
    asm volatile("s_waitcnt vmcnt(4)" ::: "memory");
    __builtin_amdgcn_s_barrier();
    __builtin_amdgcn_sched_barrier(0);

    short8 af[4][2], bl[2][2], bh[2][2];
    for (int t = 0; t < nt; ++t) {
        const int bufA = (t & 1) << 15, bufB = bufA + 16384;
        const bool pf = (t + 1) < nt;
        const int sA = ((t + 1) & 1) << 15, sB = sA + 16384;
        const unsigned short* ap = aP + (t + 1) * 64;
        const unsigned short* bp = bP + (t + 1) * 64;
        // ===== P1 : m0-3 x n0-1 =====
        #pragma unroll
        for (int m = 0; m < 4; ++m) {
            af[m][0] = *(const short8*)&LDS[bufA + aRd + m * 1024 + c0];
            af[m][1] = *(const short8*)&LDS[bufA + aRd + m * 1024 + c1];
        }
        #pragma unroll
        for (int n = 0; n < 2; ++n) {
            bl[n][0] = *(const short8*)&LDS[bufB + bRd + n * 1024 + c0];
            bl[n][1] = *(const short8*)&LDS[bufB + bRd + n * 1024 + c1];
        }
        if (pf) { gload_lds16(ap, &LDS[sA + ldsA0]);
                  gload_lds16(bp, &LDS[sB + ldsB0]); }
        __builtin_amdgcn_s_barrier();
        __builtin_amdgcn_sched_barrier(0);
        __builtin_amdgcn_s_setprio(1);
        #pragma unroll
        for (int kk = 0; kk < 2; ++kk)
            #pragma unroll
            for (int m = 0; m < 4; ++m)
                #pragma unroll
                for (int n = 0; n < 2; ++n)
                    acc[m][n] = __builtin_amdgcn_mfma_f32_16x16x32_bf16(af[m][kk], bl[n][kk], acc[m][n], 0, 0, 0);
        __builtin_amdgcn_s_setprio(0);
        asm volatile("s_waitcnt vmcnt(4)" ::: "memory");
        __builtin_amdgcn_s_barrier();
        __builtin_amdgcn_sched_barrier(0);
        // ===== P2 : m0-3 x n2-3 =====
        #pragma unroll
        for (int n = 0; n < 2; ++n) {
            bh[n][0] = *(const short8*)&LDS[bufB + bRd + (n + 2) * 1024 + c0];
            bh[n][1] = *(const short8*)&LDS[bufB + bRd + (n + 2) * 1024 + c1];
        }
        if (pf) { gload_lds16(ap + (size_t)32 * ldk, &LDS[sA + ldsA0 + 2048]);
                  gload_lds16(bp + (size_t)16 * ldk, &LDS[sB + ldsB0 + 1024]); }
        __builtin_amdgcn_s_barrier();
        __builtin_amdgcn_sched_barrier(0);
        __builtin_amdgcn_s_setprio(1);
        #pragma unroll
        for (int kk = 0; kk < 2; ++kk)
            #pragma unroll
            for (int m = 0; m < 4; ++m)
                #pragma unroll
                for (int n = 0; n < 2; ++n)
                    acc[m][n + 2] = __builtin_amdgcn_mfma_f32_16x16x32_bf16(af[m][kk], bh[n][kk], acc[m][n + 2], 0, 0, 0);
        __builtin_amdgcn_s_setprio(0);
        asm volatile("s_waitcnt vmcnt(4)" ::: "memory");
        __builtin_amdgcn_s_barrier();
        __builtin_amdgcn_sched_barrier(0);
        // ===== P3 : m4-7 x n0-1 =====
        #pragma unroll
        for (int m = 0; m < 4; ++m) {
            af[m][0] = *(const short8*)&LDS[bufA + aRd + (m + 4) * 1024 + c0];
            af[m][1] = *(const short8*)&LDS[bufA + aRd + (m + 4) * 1024 + c1];
        }
        if (pf) { gload_lds16(bp + (size_t)32 * ldk, &LDS[sB + ldsB0 + 2048]);
                  gload_lds16(bp + (size_t)48 * ldk, &LDS[sB + ldsB0 + 3072]); }
        __builtin_amdgcn_s_barrier();
        __builtin_amdgcn_sched_barrier(0);
        __builtin_amdgcn_s_setprio(1);
        #pragma unroll
        for (int kk = 0; kk < 2; ++kk)
            #pragma unroll
            for (int m = 0; m < 4; ++m)
                #pragma unroll
                for (int n = 0; n < 2; ++n)
                    acc[m + 4][n] = __builtin_amdgcn_mfma_f32_16x16x32_bf16(af[m][kk], bl[n][kk], acc[m + 4][n], 0, 0, 0);
        __builtin_amdgcn_s_setprio(0);
        __builtin_amdgcn_s_barrier();
        __builtin_amdgcn_sched_barrier(0);
        // ===== P4 : m4-7 x n2-3 =====
        if (pf) { gload_lds16(ap + (size_t)64 * ldk, &LDS[sA + ldsA0 + 4096]);
                  gload_lds16(ap + (size_t)96 * ldk, &LDS[sA + ldsA0 + 6144]); }
        __builtin_amdgcn_s_barrier();
        __builtin_amdgcn_sched_barrier(0);
        __builtin_amdgcn_s_setprio(1);
        #pragma unroll
        for (int kk = 0; kk < 2; ++kk)
            #pragma unroll
            for (int m = 0; m < 4; ++m)
                #pragma unroll
                for (int n = 0; n < 2; ++n)
                    acc[m + 4][n + 2] = __builtin_amdgcn_mfma_f32_16x16x32_bf16(af[m][kk], bh[n][kk], acc[m + 4][n + 2], 0, 0, 0);
        __builtin_amdgcn_s_setprio(0);
        asm volatile("s_waitcnt vmcnt(4)" ::: "memory");
        __builtin_amdgcn_s_barrier();
        __builtin_amdgcn_sched_barrier(0);
    }
    #pragma unroll
    for (int m = 0; m < 8; ++m)
        #pragma unroll
        for (int n = 0; n < 4; ++n)
            #pragma unroll
            for (int j = 0; j < 4; ++j) {
                int row = brow + wr * 128 + m * 16 + l4 * 4 + j;
                int col = bcol + wc * 64 + n * 16 + l15;
                Cs[(size_t)row * ldc + col] = f2bf(acc[m][n][j]);
            }
}

// ---------------- split-K reduce ----------------
__global__ void addparts(const unsigned short* __restrict__ p0,
                         const unsigned short* __restrict__ p1,
                         float* __restrict__ out) {
    int i = blockIdx.x * 256 + threadIdx.x;
    short8 a = ((const short8*)p0)[i];
    short8 b = ((const short8*)p1)[i];
    f4 lo, hi;
    #pragma unroll
    for (int j = 0; j < 4; ++j)
        lo[j] = bf2f((unsigned short)a[j]) + bf2f((unsigned short)b[j]);
    #pragma unroll
    for (int j = 0; j < 4; ++j)
        hi[j] = bf2f((unsigned short)a[j + 4]) + bf2f((unsigned short)b[j + 4]);
    ((f4*)out)[2 * i] = lo;
    ((f4*)out)[2 * i + 1] = hi;
}

// ---------------- RoPE (Q/K only; q-scale already folded into weights) ----------------
__global__ void rope_reshape(const unsigned short* __restrict__ qkv,
                             const int* __restrict__ segpos,
                             unsigned short* __restrict__ q_r,
                             unsigned short* __restrict__ k_r) {
    const int bt = blockIdx.x;
    const int hd = blockIdx.y * 2 + (threadIdx.x >> 7);  // 0..23
    const int b = bt >> 11, t = bt & 2047;
    const int h = threadIdx.x & 127;
    const unsigned short* in = (hd < 16)
        ? qkv + (size_t)bt * 4096 + hd * 128
        : qkv + (size_t)bt * 4096 + 2048 + (hd - 16) * 128;
    int pos = segpos[bt];
    int i = h & 63;
    float inv_ts = __expf((float)i * (-9.210340371976184f / 64.f));
    float ang = (float)pos * inv_ts;
    float s = __sinf(ang), c = __cosf(ang);
    float x1 = bf2f(in[i]);
    float x2 = bf2f(in[i + 64]);
    float o = (h < 64) ? (x1 * c - x2 * s) : (x2 * c + x1 * s);
    if (hd < 16) {
        q_r[((size_t)((b * 16 + hd) * 2048 + t)) * 128 + h] = f2bf(o);
    } else {
        int kh = hd - 16;
        k_r[((size_t)((b * 8 + kh) * 2048 + t)) * 128 + h] = f2bf(o);
    }
}

// ---------------- V transpose (LDS-tiled) ----------------
__global__ void v_transpose(const unsigned short* __restrict__ qkv,
                            unsigned short* __restrict__ v_t) {
    __shared__ unsigned short tile[64][72];
    const int tt0 = blockIdx.x * 64;
    const int kh = blockIdx.y >> 1, hb = (blockIdx.y & 1) * 64;
    const int b = blockIdx.z;
    int c = threadIdx.x & 63, rq = threadIdx.x >> 6;
    #pragma unroll
    for (int r = 0; r < 16; ++r) {
        int tt = r * 4 + rq;
        tile[tt][c] = qkv[(size_t)(b * 2048 + tt0 + tt) * 4096 + 3072 + kh * 128 + hb + c];
    }
    __syncthreads();
    #pragma unroll
    for (int r = 0; r < 16; ++r) {
        int hr = r * 4 + rq;
        v_t[((size_t)(b * 8 + kh) * 128 + hb + hr) * 2048 + tt0 + c] = tile[c][hr];
    }
}

// ---------------- flash attention (fixed-max softmax via soft-cap bound) ----------------

__device__ __forceinline__ void stage_kv(const unsigned short* kbase, const unsigned short* vbase,
                                         unsigned short* Ksb, unsigned short* Vtb,
                                         int st, int tid) {
    #pragma unroll
    for (int r = 0; r < 2; ++r) {
        int e = (r * 512 + tid) * 8;
        int krow = e >> 7, kcol = e & 127;
        gload_lds16(kbase + (size_t)(st * 64 + krow) * 128 + (kcol ^ ((krow & 7) << 3)), Ksb + e);
        int vrow = e >> 6, vcol = e & 63;
        gload_lds16(vbase + (size_t)vrow * 2048 + st * 64 + (vcol ^ ((vrow & 7) << 3)), Vtb + e);
    }
}

__global__ __launch_bounds__(512, 4)
void attn_kernel(const unsigned short* __restrict__ q_r,
                 const unsigned short* __restrict__ k_r,
                 const unsigned short* __restrict__ v_t,
                 unsigned short* __restrict__ enc) {
    __shared__ __align__(16) unsigned short Ks[2][64 * 128];
    __shared__ __align__(16) unsigned short Vt[2][128 * 64];
    __shared__ __align__(16) unsigned short Pl[8][16 * 64];
    const int tid = threadIdx.x, lane = tid & 63, wave = tid >> 6;
    const int l15 = lane & 15, l4 = lane >> 4;
    const int flat = blockIdx.x;
    const int xcd = flat & 7, g = flat >> 3;
    const int pair = xcd * 2 + (g >> 5);
    const int qb = 31 - (g & 31);
    const int kh = pair >> 1, b = pair & 1;
    const int n = kh * 2 + (wave >> 2);
    const int wq = wave & 3;
    short8 qf[4];
    {
        const unsigned short* qp =
            q_r + ((size_t)((b * 16 + n) * 2048 + qb * 64 + wq * 16 + l15)) * 128 + l4 * 8;
        #pragma unroll
        for (int kk = 0; kk < 4; ++kk) qf[kk] = *(const short8*)(qp + kk * 32);
    }
    f32x4 Of[8] = {};
    float lrow[4] = {};
    int t_lo = qb * 64 - 1023; if (t_lo < 0) t_lo = 0;
    const int st0 = t_lo >> 6;
    const unsigned short* kbase = k_r + (size_t)(b * 8 + kh) * 2048 * 128;
    const unsigned short* vbase = v_t + (size_t)(b * 8 + kh) * 128 * 2048;

    stage_kv(kbase, vbase, Ks[0], Vt[0], st0, tid);
    __syncthreads();
    int cur = 0;
    for (int st = st0; st <= qb; ++st) {
        if (st < qb)
            stage_kv(kbase, vbase, Ks[cur ^ 1], Vt[cur ^ 1], st + 1, tid);
        // ---- QK^T (nc-major: r4 form; kk-major measured -29us regression in r5) ----
        f32x4 sf[4] = {};
        #pragma unroll
        for (int nc = 0; nc < 4; ++nc) {
            int row = nc * 16 + l15;
            int sw = (l15 & 7) << 3;
            #pragma unroll
            for (int kk = 0; kk < 4; ++kk) {
                short8 bfr = *(const short8*)&Ks[cur][row * 128 + ((kk * 32 + l4 * 8) ^ sw)];
                sf[nc] = __builtin_amdgcn_mfma_f32_16x16x32_bf16(qf[kk], bfr, sf[nc], 0, 0, 0);
            }
        }
        // ---- softcap + fixed-max softmax: p = exp(50*tanh(x/50) - 50) ----
        const int mode = (st == qb) ? 1 : ((qb >= 16 && st == st0) ? 2 : 0);
        #pragma unroll
        for (int j = 0; j < 4; ++j) {
            int trow = qb * 64 + wq * 16 + l4 * 4 + j;
            int prow = l4 * 4 + j;
            int psw = (prow & 7) << 3;
            #pragma unroll
            for (int nc = 0; nc < 4; ++nc) {
                float ex = __expf(sf[nc][j] * 0.04f);
                float p = __expf(-100.f * __builtin_amdgcn_rcpf(ex + 1.f));
                if (mode) {
                    int s = st * 64 + nc * 16 + l15;
                    bool ok = (mode == 1) ? (s <= trow) : (s >= trow - 1023);
                    p = ok ? p : 0.f;
                }
                lrow[j] += p;
                Pl[wave][prow * 64 + ((nc * 16 + l15) ^ psw)] = f2bf(p);
            }
        }
        // ---- PV ----
        {
            int asw = (l15 & 7) << 3;
            #pragma unroll
            for (int ks = 0; ks < 2; ++ks) {
                short8 af = *(const short8*)&Pl[wave][l15 * 64 + ((ks * 32 + l4 * 8) ^ asw)];
                #pragma unroll
                for (int hc = 0; hc < 8; ++hc) {
                    int vrow = hc * 16 + l15;
                    short8 bfr = *(const short8*)&Vt[cur][vrow * 64 + ((ks * 32 + l4 * 8) ^ asw)];
                    Of[hc] = __builtin_amdgcn_mfma_f32_16x16x32_bf16(af, bfr, Of[hc], 0, 0, 0);
                }
            }
        }
        __syncthreads();
        cur ^= 1;
    }
    float inv[4];
    #pragma unroll
    for (int j = 0; j < 4; ++j) {
        float l = lrow[j];
        l += __shfl_xor(l, 1); l += __shfl_xor(l, 2);
        l += __shfl_xor(l, 4); l += __shfl_xor(l, 8);
        inv[j] = 1.f / l;
    }
    #pragma unroll
    for (int hc = 0; hc < 8; ++hc)
        #pragma unroll
        for (int j = 0; j < 4; ++j) {
            size_t row = (size_t)(b * 2048 + qb * 64 + wq * 16 + l4 * 4 + j);
            enc[row * 2048 + n * 128 + hc * 16 + l15] = f2bf(Of[hc][j] * inv[j]);
        }
}

// ---------------- launch ----------------

extern "C" void kernel_launch(void* const* d_in, const int* in_sizes, int n_in,
                              void* d_out, int out_size, void* d_ws, size_t ws_size,
                              hipStream_t stream) {
    const float* x   = (const float*)d_in[0];
    const int* segp  = (const int*)d_in[1];
    const float* wq  = (const float*)d_in[3];
    const float* wkv = (const float*)d_in[4];
    const float* wo  = (const float*)d_in[5];
    float* out = (float*)d_out;
    char* ws = (char*)d_ws;
    if (ws_size < ((size_t)96 << 20)) return;

    unsigned short* xb    = (unsigned short*)(ws);                       // 16 MiB
    unsigned short* wqkvt = (unsigned short*)(ws + ((size_t)16 << 20));  // 16 MiB
    unsigned short* qkv   = (unsigned short*)(ws + ((size_t)32 << 20));  // 32 MiB
    unsigned short* q_r   = (unsigned short*)(ws + ((size_t)64 << 20));  // 16 MiB
    unsigned short* k_r   = (unsigned short*)(ws + ((size_t)80 << 20));  // 8 MiB
    unsigned short* v_t   = (unsigned short*)(ws + ((size_t)88 << 20));  // 8 MiB
    unsigned short* wo_t  = (unsigned short*)(ws + ((size_t)16 << 20));  // reuse wqkvt
    unsigned short* enc   = (unsigned short*)(ws + ((size_t)32 << 20));  // reuse qkv
    unsigned short* part  = (unsigned short*)(ws + ((size_t)64 << 20));  // 32 MiB, reuse q_r/k_r/v_t

    conv_x<<<8192, 256, 0, stream>>>(x, xb);
    conv_wqkvt<<<dim3(32, 64), 256, 0, stream>>>(wq, wkv, wqkvt);
    gemm8p<<<dim3(16, 16), 512, 0, stream>>>(xb, wqkvt, qkv, 2048, 4096, 32, 0, 0);
    rope_reshape<<<dim3(4096, 12), 256, 0, stream>>>(qkv, segp, q_r, k_r);
    v_transpose<<<dim3(32, 16, 2), 256, 0, stream>>>(qkv, v_t);
    conv_wot<<<dim3(32, 32), 256, 0, stream>>>(wo, wo_t);
    attn_kernel<<<512, 512, 0, stream>>>(q_r, k_r, v_t, enc);
    gemm8p<<<dim3(8, 32), 512, 0, stream>>>(enc, wo_t, part, 2048, 2048, 16, 1, (size_t)4096 * 2048);
    addparts<<<4096, 256, 0, stream>>>(part, part + (size_t)4096 * 2048, out);
}

// Round 7
// 215.146 us; speedup vs baseline: 1.0074x; 1.0047x over previous
//
#include <hip/hip_runtime.h>

typedef __attribute__((ext_vector_type(8))) short short8;
typedef __attribute__((ext_vector_type(4))) float f32x4;
typedef __attribute__((ext_vector_type(4))) float f4;
typedef __attribute__((ext_vector_type(4))) unsigned short u16x4;

__device__ __forceinline__ unsigned short f2bf(float f) {
    union { float f; unsigned int u; } v; v.f = f;
    unsigned int r = v.u + 0x7fffu + ((v.u >> 16) & 1u);
    return (unsigned short)(r >> 16);
}
__device__ __forceinline__ float bf2f(unsigned short h) {
    union { unsigned int u; float f; } v; v.u = ((unsigned int)h) << 16;
    return v.f;
}
__device__ __forceinline__ float fexp2(float x) {
    float r; asm("v_exp_f32 %0, %1" : "=v"(r) : "v"(x)); return r;
}
__device__ __forceinline__ void gload_lds16(const void* g, void* l) {
    __builtin_amdgcn_global_load_lds(
        (const __attribute__((address_space(1))) unsigned int*)g,
        (__attribute__((address_space(3))) unsigned int*)l, 16, 0, 0);
}

// ---------------- conversions ----------------

__global__ void conv_x(const float* __restrict__ x, unsigned short* __restrict__ xb) {
    int i = blockIdx.x * 256 + threadIdx.x;
    f4 v = ((const f4*)x)[i];
    u16x4 o;
    o[0] = f2bf(v[0]); o[1] = f2bf(v[1]); o[2] = f2bf(v[2]); o[3] = f2bf(v[3]);
    ((u16x4*)xb)[i] = o;
}

// QUERY_SCALE folded into q-head weights (rope is linear; scale commutes)
__global__ void conv_wqkvt(const float* __restrict__ wq, const float* __restrict__ wkv,
                           unsigned short* __restrict__ wt) {
    __shared__ float tile[64 * 65];
    const int d0 = blockIdx.x * 64, f0 = blockIdx.y * 64;
    const int head = f0 >> 7;
    const int h0 = f0 & 127;
    const float* src;
    float scl;
    if (head < 16) { src = wq + (size_t)head * 2048 * 128; scl = 0.08838834764831845f; }
    else           { src = wkv + (size_t)(head - 16) * 2048 * 128; scl = 1.f; }
    {
        int hh = threadIdx.x & 63, dq = threadIdx.x >> 6;
        #pragma unroll
        for (int r = 0; r < 16; ++r) {
            int dd = r * 4 + dq;
            tile[dd * 65 + hh] = src[(size_t)(d0 + dd) * 128 + h0 + hh] * scl;
        }
    }
    __syncthreads();
    {
        int dd = threadIdx.x & 63, fq = threadIdx.x >> 6;
        #pragma unroll
        for (int r = 0; r < 16; ++r) {
            int fl = r * 4 + fq;
            wt[(size_t)(f0 + fl) * 2048 + d0 + dd] = f2bf(tile[dd * 65 + fl]);
        }
    }
}

__global__ void conv_wot(const float* __restrict__ wo, unsigned short* __restrict__ wt) {
    __shared__ float tile[64 * 65];
    const int d0 = blockIdx.x * 64, r0 = blockIdx.y * 64;
    int cc = threadIdx.x & 63, rq = threadIdx.x >> 6;
    #pragma unroll
    for (int r = 0; r < 16; ++r) {
        int rr = r * 4 + rq;
        tile[rr * 65 + cc] = wo[(size_t)(r0 + rr) * 2048 + d0 + cc];
    }
    __syncthreads();
    #pragma unroll
    for (int r = 0; r < 16; ++r) {
        int rr = r * 4 + rq;
        wt[(size_t)(d0 + rr) * 2048 + r0 + cc] = f2bf(tile[cc * 65 + rr]);
    }
}

// ---------------- 8-phase 256x256 GEMM, deep-prefetch schedule ----------------
// Region-level refill: each LDS region is re-staged the phase AFTER its last read,
// giving every global_load_lds 5-7 phases in flight before its vmcnt (FIFO-verified):
//   P1 issues A-hi(t+1); P2: A-lo0/B0(t+2, into CURRENT buf); P3: A-lo1/B1(t+2);
//   P4: B2/B3(t+2). vmcnt(6) at each phase end; epilogue tile drained + barrier-free.

__global__ __launch_bounds__(512, 2)
void gemm8p(const unsigned short* __restrict__ A,
            const unsigned short* __restrict__ Bt,
            unsigned short* __restrict__ C,
            int ldk, int ldc, int nt, int ksplit, size_t cstride) {
    __shared__ __align__(16) unsigned short LDS[65536];
    const int tid = threadIdx.x, lane = tid & 63, w = tid >> 6;
    const int wr = w >> 2, wc = w & 3;
    const int l15 = lane & 15, l4 = lane >> 4;
    int nwg = gridDim.x * gridDim.y;
    int wg = blockIdx.y * gridDim.x + blockIdx.x;
    int swz = (wg & 7) * (nwg >> 3) + (wg >> 3);
    int bx = swz % gridDim.x, by = swz / gridDim.x;
    int slice = 0;
    if (ksplit) { slice = by & 1; by >>= 1; }
    unsigned short* Cs = C + (size_t)slice * cstride;
    const int brow = by * 256, bcol = bx * 256;
    const size_t koff = (size_t)slice * nt * 64;
    const int wg_a = w & 3;
    const int wg_b = wr;
    const int rA = wg_a * 8 + (lane >> 3);
    const int rB = wg_b * 8 + (lane >> 3);
    const int cgS = ((lane & 7) ^ (lane >> 3)) * 8;
    const unsigned short* aP = A + (size_t)(brow + wr * 128 + rA) * ldk + koff + cgS;
    const unsigned short* bP = Bt + (size_t)(bcol + wc * 64 + rB) * ldk + koff + cgS;
    const int ldsA0 = wr * 8192 + (wg_a * 64 + lane) * 8;
    const int ldsB0 = wc * 4096 + (wg_b * 64 + lane) * 8;
    const int aRd = (wr * 128 + l15) * 64;
    const int bRd = (wc * 64 + l15) * 64;
    const int c0 = ((0 + l4) ^ (l15 & 7)) * 8;
    const int c1 = ((4 + l4) ^ (l15 & 7)) * 8;
    f32x4 acc[8][4] = {};
    // ---- prologue: all of tile0 + L1..L6 of tile1 ----
    gload_lds16(aP,                    &LDS[ldsA0]);
    gload_lds16(bP,                    &LDS[16384 + ldsB0]);
    gload_lds16(aP + (size_t)32 * ldk, &LDS[ldsA0 + 2048]);
    gload_lds16(bP + (size_t)16 * ldk, &LDS[16384 + ldsB0 + 1024]);
    gload_lds16(bP + (size_t)32 * ldk, &LDS[16384 + ldsB0 + 2048]);
    gload_lds16(bP + (size_t)48 * ldk, &LDS[16384 + ldsB0 + 3072]);
    gload_lds16(aP + (size_t)64 * ldk, &LDS[ldsA0 + 4096]);
    gload_lds16(aP + (size_t)96 * ldk, &LDS[ldsA0 + 6144]);
    {
        const unsigned short* a1 = aP + 64;
        const unsigned short* b1 = bP + 64;
        gload_lds16(a1,                    &LDS[32768 + ldsA0]);
        gload_lds16(b1,                    &LDS[49152 + ldsB0]);
        gload_lds16(a1 + (size_t)32 * ldk, &LDS[32768 + ldsA0 + 2048]);
        gload_lds16(b1 + (size_t)16 * ldk, &LDS[49152 + ldsB0 + 1024]);
        gload_lds16(b1 + (size_t)32 * ldk, &LDS[49152 + ldsB0 + 2048]);
        gload_lds16(b1 + (size_t)48 * ldk, &LDS[49152 + ldsB0 + 3072]);
    }
    asm volatile("s_waitcnt vmcnt(6)" ::: "memory");  // tile0 fully landed
    __builtin_amdgcn_s_barrier();
    __builtin_amdgcn_sched_barrier(0);

    short8 af[4][2], bl[2][2], bh[2][2];
    for (int t = 0; t < nt - 1; ++t) {
        const int bufA = (t & 1) << 15, bufB = bufA + 16384;
        const int sA = ((t + 1) & 1) << 15;                  // other buf (tile t+1)
        const bool pf2 = (t + 2) < nt;
        const unsigned short* ap1 = aP + (size_t)(t + 1) * 64;
        const unsigned short* ap2 = aP + (size_t)(t + 2) * 64;
        const unsigned short* bp2 = bP + (size_t)(t + 2) * 64;
        // ===== P1 : m0-3 x n0-1 ; issue A-hi(t+1) =====
        #pragma unroll
        for (int m = 0; m < 4; ++m) {
            af[m][0] = *(const short8*)&LDS[bufA + aRd + m * 1024 + c0];
            af[m][1] = *(const short8*)&LDS[bufA + aRd + m * 1024 + c1];
        }
        #pragma unroll
        for (int n = 0; n < 2; ++n) {
            bl[n][0] = *(const short8*)&LDS[bufB + bRd + n * 1024 + c0];
            bl[n][1] = *(const short8*)&LDS[bufB + bRd + n * 1024 + c1];
        }
        gload_lds16(ap1 + (size_t)64 * ldk, &LDS[sA + ldsA0 + 4096]);
        gload_lds16(ap1 + (size_t)96 * ldk, &LDS[sA + ldsA0 + 6144]);
        __builtin_amdgcn_s_barrier();
        __builtin_amdgcn_sched_barrier(0);
        __builtin_amdgcn_s_setprio(1);
        #pragma unroll
        for (int kk = 0; kk < 2; ++kk)
            #pragma unroll
            for (int m = 0; m < 4; ++m)
                #pragma unroll
                for (int n = 0; n < 2; ++n)
                    acc[m][n] = __builtin_amdgcn_mfma_f32_16x16x32_bf16(af[m][kk], bl[n][kk], acc[m][n], 0, 0, 0);
        __builtin_amdgcn_s_setprio(0);
        asm volatile("s_waitcnt vmcnt(6)" ::: "memory");
        __builtin_amdgcn_s_barrier();
        __builtin_amdgcn_sched_barrier(0);
        // ===== P2 : m0-3 x n2-3 ; issue A-lo0/B0(t+2) into CURRENT buf =====
        #pragma unroll
        for (int n = 0; n < 2; ++n) {
            bh[n][0] = *(const short8*)&LDS[bufB + bRd + (n + 2) * 1024 + c0];
            bh[n][1] = *(const short8*)&LDS[bufB + bRd + (n + 2) * 1024 + c1];
        }
        if (pf2) { gload_lds16(ap2, &LDS[bufA + ldsA0]);
                   gload_lds16(bp2, &LDS[bufB + ldsB0]); }
        __builtin_amdgcn_s_barrier();
        __builtin_amdgcn_sched_barrier(0);
        __builtin_amdgcn_s_setprio(1);
        #pragma unroll
        for (int kk = 0; kk < 2; ++kk)
            #pragma unroll
            for (int m = 0; m < 4; ++m)
                #pragma unroll
                for (int n = 0; n < 2; ++n)
                    acc[m][n + 2] = __builtin_amdgcn_mfma_f32_16x16x32_bf16(af[m][kk], bh[n][kk], acc[m][n + 2], 0, 0, 0);
        __builtin_amdgcn_s_setprio(0);
        asm volatile("s_waitcnt vmcnt(6)" ::: "memory");
        __builtin_amdgcn_s_barrier();
        __builtin_amdgcn_sched_barrier(0);
        // ===== P3 : m4-7 x n0-1 ; issue A-lo1/B1(t+2) =====
        #pragma unroll
        for (int m = 0; m < 4; ++m) {
            af[m][0] = *(const short8*)&LDS[bufA + aRd + (m + 4) * 1024 + c0];
            af[m][1] = *(const short8*)&LDS[bufA + aRd + (m + 4) * 1024 + c1];
        }
        if (pf2) { gload_lds16(ap2 + (size_t)32 * ldk, &LDS[bufA + ldsA0 + 2048]);
                   gload_lds16(bp2 + (size_t)16 * ldk, &LDS[bufB + ldsB0 + 1024]); }
        __builtin_amdgcn_s_barrier();
        __builtin_amdgcn_sched_barrier(0);
        __builtin_amdgcn_s_setprio(1);
        #pragma unroll
        for (int kk = 0; kk < 2; ++kk)
            #pragma unroll
            for (int m = 0; m < 4; ++m)
                #pragma unroll
                for (int n = 0; n < 2; ++n)
                    acc[m + 4][n] = __builtin_amdgcn_mfma_f32_16x16x32_bf16(af[m][kk], bl[n][kk], acc[m + 4][n], 0, 0, 0);
        __builtin_amdgcn_s_setprio(0);
        asm volatile("s_waitcnt vmcnt(6)" ::: "memory");
        __builtin_amdgcn_s_barrier();
        __builtin_amdgcn_sched_barrier(0);
        // ===== P4 : m4-7 x n2-3 ; issue B2/B3(t+2) =====
        if (pf2) { gload_lds16(bp2 + (size_t)32 * ldk, &LDS[bufB + ldsB0 + 2048]);
                   gload_lds16(bp2 + (size_t)48 * ldk, &LDS[bufB + ldsB0 + 3072]); }
        __builtin_amdgcn_s_barrier();
        __builtin_amdgcn_sched_barrier(0);
        __builtin_amdgcn_s_setprio(1);
        #pragma unroll
        for (int kk = 0; kk < 2; ++kk)
            #pragma unroll
            for (int m = 0; m < 4; ++m)
                #pragma unroll
                for (int n = 0; n < 2; ++n)
                    acc[m + 4][n + 2] = __builtin_amdgcn_mfma_f32_16x16x32_bf16(af[m][kk], bh[n][kk], acc[m + 4][n + 2], 0, 0, 0);
        __builtin_amdgcn_s_setprio(0);
        asm volatile("s_waitcnt vmcnt(6)" ::: "memory");
        __builtin_amdgcn_s_barrier();
        __builtin_amdgcn_sched_barrier(0);
    }
    // ---- epilogue tile nt-1: drain, then barrier-free compute ----
    asm volatile("s_waitcnt vmcnt(0)" ::: "memory");
    __builtin_amdgcn_s_barrier();
    {
        const int bufA = ((nt - 1) & 1) << 15, bufB = bufA + 16384;
        #pragma unroll
        for (int m = 0; m < 4; ++m) {
            af[m][0] = *(const short8*)&LDS[bufA + aRd + m * 1024 + c0];
            af[m][1] = *(const short8*)&LDS[bufA + aRd + m * 1024 + c1];
        }
        #pragma unroll
        for (int n = 0; n < 2; ++n) {
            bl[n][0] = *(const short8*)&LDS[bufB + bRd + n * 1024 + c0];
            bl[n][1] = *(const short8*)&LDS[bufB + bRd + n * 1024 + c1];
            bh[n][0] = *(const short8*)&LDS[bufB + bRd + (n + 2) * 1024 + c0];
            bh[n][1] = *(const short8*)&LDS[bufB + bRd + (n + 2) * 1024 + c1];
        }
        #pragma unroll
        for (int kk = 0; kk < 2; ++kk)
            #pragma unroll
            for (int m = 0; m < 4; ++m)
                #pragma unroll
                for (int n = 0; n < 2; ++n) {
                    acc[m][n]     = __builtin_amdgcn_mfma_f32_16x16x32_bf16(af[m][kk], bl[n][kk], acc[m][n], 0, 0, 0);
                    acc[m][n + 2] = __builtin_amdgcn_mfma_f32_16x16x32_bf16(af[m][kk], bh[n][kk], acc[m][n + 2], 0, 0, 0);
                }
        #pragma unroll
        for (int m = 0; m < 4; ++m) {
            af[m][0] = *(const short8*)&LDS[bufA + aRd + (m + 4) * 1024 + c0];
            af[m][1] = *(const short8*)&LDS[bufA + aRd + (m + 4) * 1024 + c1];
        }
        #pragma unroll
        for (int kk = 0; kk < 2; ++kk)
            #pragma unroll
            for (int m = 0; m < 4; ++m)
                #pragma unroll
                for (int n = 0; n < 2; ++n) {
                    acc[m + 4][n]     = __builtin_amdgcn_mfma_f32_16x16x32_bf16(af[m][kk], bl[n][kk], acc[m + 4][n], 0, 0, 0);
                    acc[m + 4][n + 2] = __builtin_amdgcn_mfma_f32_16x16x32_bf16(af[m][kk], bh[n][kk], acc[m + 4][n + 2], 0, 0, 0);
                }
    }
    #pragma unroll
    for (int m = 0; m < 8; ++m)
        #pragma unroll
        for (int n = 0; n < 4; ++n)
            #pragma unroll
            for (int j = 0; j < 4; ++j) {
                int row = brow + wr * 128 + m * 16 + l4 * 4 + j;
                int col = bcol + wc * 64 + n * 16 + l15;
                Cs[(size_t)row * ldc + col] = f2bf(acc[m][n][j]);
            }
}

// ---------------- split-K reduce ----------------
__global__ void addparts(const unsigned short* __restrict__ p0,
                         const unsigned short* __restrict__ p1,
                         float* __restrict__ out) {
    int i = blockIdx.x * 256 + threadIdx.x;
    short8 a = ((const short8*)p0)[i];
    short8 b = ((const short8*)p1)[i];
    f4 lo, hi;
    #pragma unroll
    for (int j = 0; j < 4; ++j)
        lo[j] = bf2f((unsigned short)a[j]) + bf2f((unsigned short)b[j]);
    #pragma unroll
    for (int j = 0; j < 4; ++j)
        hi[j] = bf2f((unsigned short)a[j + 4]) + bf2f((unsigned short)b[j + 4]);
    ((f4*)out)[2 * i] = lo;
    ((f4*)out)[2 * i + 1] = hi;
}

// ---------------- RoPE (Q/K only; q-scale folded into weights) ----------------
__global__ void rope_reshape(const unsigned short* __restrict__ qkv,
                             const int* __restrict__ segpos,
                             unsigned short* __restrict__ q_r,
                             unsigned short* __restrict__ k_r) {
    const int bt = blockIdx.x;
    const int hd = blockIdx.y * 2 + (threadIdx.x >> 7);  // 0..23
    const int b = bt >> 11, t = bt & 2047;
    const int h = threadIdx.x & 127;
    const unsigned short* in = (hd < 16)
        ? qkv + (size_t)bt * 4096 + hd * 128
        : qkv + (size_t)bt * 4096 + 2048 + (hd - 16) * 128;
    int pos = segpos[bt];
    int i = h & 63;
    float inv_ts = __expf((float)i * (-9.210340371976184f / 64.f));
    float ang = (float)pos * inv_ts;
    float s = __sinf(ang), c = __cosf(ang);
    float x1 = bf2f(in[i]);
    float x2 = bf2f(in[i + 64]);
    float o = (h < 64) ? (x1 * c - x2 * s) : (x2 * c + x1 * s);
    if (hd < 16) {
        q_r[((size_t)((b * 16 + hd) * 2048 + t)) * 128 + h] = f2bf(o);
    } else {
        int kh = hd - 16;
        k_r[((size_t)((b * 8 + kh) * 2048 + t)) * 128 + h] = f2bf(o);
    }
}

// ---------------- V transpose (LDS-tiled) ----------------
__global__ void v_transpose(const unsigned short* __restrict__ qkv,
                            unsigned short* __restrict__ v_t) {
    __shared__ unsigned short tile[64][72];
    const int tt0 = blockIdx.x * 64;
    const int kh = blockIdx.y >> 1, hb = (blockIdx.y & 1) * 64;
    const int b = blockIdx.z;
    int c = threadIdx.x & 63, rq = threadIdx.x >> 6;
    #pragma unroll
    for (int r = 0; r < 16; ++r) {
        int tt = r * 4 + rq;
        tile[tt][c] = qkv[(size_t)(b * 2048 + tt0 + tt) * 4096 + 3072 + kh * 128 + hb + c];
    }
    __syncthreads();
    #pragma unroll
    for (int r = 0; r < 16; ++r) {
        int hr = r * 4 + rq;
        v_t[((size_t)(b * 8 + kh) * 128 + hb + hr) * 2048 + tt0 + c] = tile[c][hr];
    }
}

// ---------------- flash attention (fixed-max softmax via soft-cap bound) ----------------

__device__ __forceinline__ void stage_kv(const unsigned short* kbase, const unsigned short* vbase,
                                         unsigned short* Ksb, unsigned short* Vtb,
                                         int st, int tid) {
    #pragma unroll
    for (int r = 0; r < 2; ++r) {
        int e = (r * 512 + tid) * 8;
        int krow = e >> 7, kcol = e & 127;
        gload_lds16(kbase + (size_t)(st * 64 + krow) * 128 + (kcol ^ ((krow & 7) << 3)), Ksb + e);
        int vrow = e >> 6, vcol = e & 63;
        gload_lds16(vbase + (size_t)vrow * 2048 + st * 64 + (vcol ^ ((vrow & 7) << 3)), Vtb + e);
    }
}

__global__ __launch_bounds__(512, 4)
void attn_kernel(const unsigned short* __restrict__ q_r,
                 const unsigned short* __restrict__ k_r,
                 const unsigned short* __restrict__ v_t,
                 unsigned short* __restrict__ enc) {
    __shared__ __align__(16) unsigned short Ks[2][64 * 128];
    __shared__ __align__(16) unsigned short Vt[2][128 * 64];
    __shared__ __align__(16) unsigned short Pl[8][16 * 64];
    const int tid = threadIdx.x, lane = tid & 63, wave = tid >> 6;
    const int l15 = lane & 15, l4 = lane >> 4;
    const int flat = blockIdx.x;
    const int xcd = flat & 7, g = flat >> 3;
    const int pair = xcd * 2 + (g >> 5);
    const int qb = 31 - (g & 31);
    const int kh = pair >> 1, b = pair & 1;
    const int n = kh * 2 + (wave >> 2);
    const int wq = wave & 3;
    short8 qf[4];
    {
        const unsigned short* qp =
            q_r + ((size_t)((b * 16 + n) * 2048 + qb * 64 + wq * 16 + l15)) * 128 + l4 * 8;
        #pragma unroll
        for (int kk = 0; kk < 4; ++kk) qf[kk] = *(const short8*)(qp + kk * 32);
    }
    f32x4 Of[8] = {};
    float lrow[4] = {};
    int t_lo = qb * 64 - 1023; if (t_lo < 0) t_lo = 0;
    const int st0 = t_lo >> 6;
    const unsigned short* kbase = k_r + (size_t)(b * 8 + kh) * 2048 * 128;
    const unsigned short* vbase = v_t + (size_t)(b * 8 + kh) * 128 * 2048;

    stage_kv(kbase, vbase, Ks[0], Vt[0], st0, tid);
    __syncthreads();
    int cur = 0;
    for (int st = st0; st <= qb; ++st) {
        if (st < qb)
            stage_kv(kbase, vbase, Ks[cur ^ 1], Vt[cur ^ 1], st + 1, tid);
        // ---- QK^T ----
        f32x4 sf[4] = {};
        __builtin_amdgcn_s_setprio(1);
        #pragma unroll
        for (int nc = 0; nc < 4; ++nc) {
            int row = nc * 16 + l15;
            int sw = (l15 & 7) << 3;
            #pragma unroll
            for (int kk = 0; kk < 4; ++kk) {
                short8 bfr = *(const short8*)&Ks[cur][row * 128 + ((kk * 32 + l4 * 8) ^ sw)];
                sf[nc] = __builtin_amdgcn_mfma_f32_16x16x32_bf16(qf[kk], bfr, sf[nc], 0, 0, 0);
            }
        }
        __builtin_amdgcn_s_setprio(0);
        // ---- softcap + fixed-max softmax: p = 2^(-144.27 / (2^(0.0577*s) + 1)) ----
        const int mode = (st == qb) ? 1 : ((qb >= 16 && st == st0) ? 2 : 0);
        #pragma unroll
        for (int j = 0; j < 4; ++j) {
            int trow = qb * 64 + wq * 16 + l4 * 4 + j;
            int prow = l4 * 4 + j;
            int psw = (prow & 7) << 3;
            #pragma unroll
            for (int nc = 0; nc < 4; ++nc) {
                float ex = fexp2(sf[nc][j] * 0.057707801635558534f);
                float p = fexp2(-144.26950408889634f * __builtin_amdgcn_rcpf(ex + 1.f));
                if (mode) {
                    int s = st * 64 + nc * 16 + l15;
                    bool ok = (mode == 1) ? (s <= trow) : (s >= trow - 1023);
                    p = ok ? p : 0.f;
                }
                lrow[j] += p;
                Pl[wave][prow * 64 + ((nc * 16 + l15) ^ psw)] = f2bf(p);
            }
        }
        // ---- PV ----
        {
            int asw = (l15 & 7) << 3;
            __builtin_amdgcn_s_setprio(1);
            #pragma unroll
            for (int ks = 0; ks < 2; ++ks) {
                short8 af = *(const short8*)&Pl[wave][l15 * 64 + ((ks * 32 + l4 * 8) ^ asw)];
                #pragma unroll
                for (int hc = 0; hc < 8; ++hc) {
                    int vrow = hc * 16 + l15;
                    short8 bfr = *(const short8*)&Vt[cur][vrow * 64 + ((ks * 32 + l4 * 8) ^ asw)];
                    Of[hc] = __builtin_amdgcn_mfma_f32_16x16x32_bf16(af, bfr, Of[hc], 0, 0, 0);
                }
            }
            __builtin_amdgcn_s_setprio(0);
        }
        __syncthreads();
        cur ^= 1;
    }
    float inv[4];
    #pragma unroll
    for (int j = 0; j < 4; ++j) {
        float l = lrow[j];
        l += __shfl_xor(l, 1); l += __shfl_xor(l, 2);
        l += __shfl_xor(l, 4); l += __shfl_xor(l, 8);
        inv[j] = 1.f / l;
    }
    #pragma unroll
    for (int hc = 0; hc < 8; ++hc)
        #pragma unroll
        for (int j = 0; j < 4; ++j) {
            size_t row = (size_t)(b * 2048 + qb * 64 + wq * 16 + l4 * 4 + j);
            enc[row * 2048 + n * 128 + hc * 16 + l15] = f2bf(Of[hc][j] * inv[j]);
        }
}

// ---------------- launch ----------------

extern "C" void kernel_launch(void* const* d_in, const int* in_sizes, int n_in,
                              void* d_out, int out_size, void* d_ws, size_t ws_size,
                              hipStream_t stream) {
    const float* x   = (const float*)d_in[0];
    const int* segp  = (const int*)d_in[1];
    const float* wq  = (const float*)d_in[3];
    const float* wkv = (const float*)d_in[4];
    const float* wo  = (const float*)d_in[5];
    float* out = (float*)d_out;
    char* ws = (char*)d_ws;
    if (ws_size < ((size_t)96 << 20)) return;

    unsigned short* xb    = (unsigned short*)(ws);                       // 16 MiB
    unsigned short* wqkvt = (unsigned short*)(ws + ((size_t)16 << 20));  // 16 MiB
    unsigned short* qkv   = (unsigned short*)(ws + ((size_t)32 << 20));  // 32 MiB
    unsigned short* q_r   = (unsigned short*)(ws + ((size_t)64 << 20));  // 16 MiB
    unsigned short* k_r   = (unsigned short*)(ws + ((size_t)80 << 20));  // 8 MiB
    unsigned short* v_t   = (unsigned short*)(ws + ((size_t)88 << 20));  // 8 MiB
    unsigned short* wo_t  = (unsigned short*)(ws + ((size_t)16 << 20));  // reuse wqkvt
    unsigned short* enc   = (unsigned short*)(ws + ((size_t)32 << 20));  // reuse qkv
    unsigned short* part  = (unsigned short*)(ws + ((size_t)64 << 20));  // 32 MiB, reuse q_r/k_r/v_t

    conv_x<<<8192, 256, 0, stream>>>(x, xb);
    conv_wqkvt<<<dim3(32, 64), 256, 0, stream>>>(wq, wkv, wqkvt);
    gemm8p<<<dim3(16, 16), 512, 0, stream>>>(xb, wqkvt, qkv, 2048, 4096, 32, 0, 0);
    rope_reshape<<<dim3(4096, 12), 256, 0, stream>>>(qkv, segp, q_r, k_r);
    v_transpose<<<dim3(32, 16, 2), 256, 0, stream>>>(qkv, v_t);
    conv_wot<<<dim3(32, 32), 256, 0, stream>>>(wo, wo_t);
    attn_kernel<<<512, 512, 0, stream>>>(q_r, k_r, v_t, enc);
    gemm8p<<<dim3(8, 32), 512, 0, stream>>>(enc, wo_t, part, 2048, 2048, 16, 1, (size_t)4096 * 2048);
    addparts<<<4096, 256, 0, stream>>>(part, part + (size_t)4096 * 2048, out);
}